// Round 2
// baseline (88.210 us; speedup 1.0000x reference)
//
#include <hip/hip_runtime.h>

#define NBINS 1536            // 2 * 24 * 32
#define NSUB  2               // one LDS sub-histogram per PAIR of waves (12 KiB)
#define HIST_BLOCKS 2048      // 8 blocks/CU resident -> 32 waves/CU (full occupancy)
#define HIST_THREADS 256

typedef float vfloat4 __attribute__((ext_vector_type(4)));

__global__ void zero_hist_kernel(unsigned int* __restrict__ g) {
    int i = blockIdx.x * blockDim.x + threadIdx.x;
    if (i < NBINS) g[i] = 0u;
}

__device__ __forceinline__ void bin_event(vfloat4 e, unsigned int* sub) {
    // replicate ref bit-exactly: f32 mul by BINS/SENSOR (both = 0.05f), trunc, clip
    int xb = (int)(e.x * (32.0f / 640.0f));
    int yb = (int)(e.y * (24.0f / 480.0f));
    xb = min(max(xb, 0), 31);
    yb = min(max(yb, 0), 23);
    int p = (e.w > 0.0f) ? 0 : 768;             // 768 = 24*32
    atomicAdd(&sub[p + (yb << 5) + xb], 1u);
}

__global__ __launch_bounds__(HIST_THREADS)
void event_hist_kernel(const vfloat4* __restrict__ ev, unsigned int* __restrict__ g, int n) {
    __shared__ unsigned int lh[NSUB * NBINS];   // 12 KiB
    for (int i = threadIdx.x; i < NSUB * NBINS; i += HIST_THREADS) lh[i] = 0u;
    __syncthreads();

    unsigned int* mysub = &lh[(threadIdx.x >> 7) * NBINS];  // waves {0,1}->sub0, {2,3}->sub1
    const int stride = gridDim.x * HIST_THREADS;
    int i = blockIdx.x * HIST_THREADS + threadIdx.x;
    for (; i + stride < n; i += 2 * stride) {
        vfloat4 a = __builtin_nontemporal_load(&ev[i]);          // two independent
        vfloat4 b = __builtin_nontemporal_load(&ev[i + stride]); // loads in flight
        bin_event(a, mysub);
        bin_event(b, mysub);
    }
    if (i < n) {
        vfloat4 a = __builtin_nontemporal_load(&ev[i]);
        bin_event(a, mysub);
    }
    __syncthreads();

    // flush block-local sums to the global histogram
    for (int i2 = threadIdx.x; i2 < NBINS; i2 += HIST_THREADS) {
        unsigned int s = lh[i2] + lh[NBINS + i2];
        atomicAdd(&g[i2], s);
    }
}

__global__ void normalize_kernel(const unsigned int* __restrict__ g,
                                 float* __restrict__ out, float total) {
    int i = blockIdx.x * blockDim.x + threadIdx.x;
    if (i < NBINS) out[i] = (float)g[i] / total;  // counts exact ints; total exact in f32
}

extern "C" void kernel_launch(void* const* d_in, const int* in_sizes, int n_in,
                              void* d_out, int out_size, void* d_ws, size_t ws_size,
                              hipStream_t stream) {
    const vfloat4* ev = (const vfloat4*)d_in[0]; // events [N,4] row-major -> one float4/event
    const int n = in_sizes[0] / 4;
    unsigned int* g = (unsigned int*)d_ws;       // 6 KiB of workspace
    float* out = (float*)d_out;

    zero_hist_kernel<<<(NBINS + 255) / 256, 256, 0, stream>>>(g);
    event_hist_kernel<<<HIST_BLOCKS, HIST_THREADS, 0, stream>>>(ev, g, n);
    normalize_kernel<<<(NBINS + 255) / 256, 256, 0, stream>>>(g, out, (float)n);
}

// Round 3
// 69.937 us; speedup vs baseline: 1.2613x; 1.2613x over previous
//
#include <hip/hip_runtime.h>

#define NBINS 1536            // 2 * 24 * 32
#define NSUB  4               // one LDS sub-histogram per PAIR of waves (24 KiB, 8 waves/block)
#define HIST_BLOCKS 1024      // 4 blocks/CU resident x 8 waves = 32 waves/CU (full occupancy)
#define HIST_THREADS 512

typedef float vfloat4 __attribute__((ext_vector_type(4)));

__global__ void zero_hist_kernel(unsigned int* __restrict__ g) {
    int i = blockIdx.x * blockDim.x + threadIdx.x;
    if (i < NBINS) g[i] = 0u;
}

__device__ __forceinline__ void bin_event(vfloat4 e, unsigned int* sub) {
    // replicate ref bit-exactly: f32 mul by BINS/SENSOR (both = 0.05f), trunc, clip
    int xb = (int)(e.x * (32.0f / 640.0f));
    int yb = (int)(e.y * (24.0f / 480.0f));
    xb = min(max(xb, 0), 31);
    yb = min(max(yb, 0), 23);
    int p = (e.w > 0.0f) ? 0 : 768;             // 768 = 24*32
    atomicAdd(&sub[p + (yb << 5) + xb], 1u);
}

__global__ __launch_bounds__(HIST_THREADS)
void event_hist_kernel(const vfloat4* __restrict__ ev, unsigned int* __restrict__ g, int n) {
    __shared__ unsigned int lh[NSUB * NBINS];   // 24 KiB
    for (int i = threadIdx.x; i < NSUB * NBINS; i += HIST_THREADS) lh[i] = 0u;
    __syncthreads();

    unsigned int* mysub = &lh[(threadIdx.x >> 7) * NBINS];  // 2 waves per sub-histogram
    const int stride = gridDim.x * HIST_THREADS;
    int i = blockIdx.x * HIST_THREADS + threadIdx.x;
    for (; i + stride < n; i += 2 * stride) {
        vfloat4 a = ev[i];            // two independent loads in flight
        vfloat4 b = ev[i + stride];
        bin_event(a, mysub);
        bin_event(b, mysub);
    }
    if (i < n) {
        vfloat4 a = ev[i];
        bin_event(a, mysub);
    }
    __syncthreads();

    // flush block-local sums to the global histogram (3 bins per thread)
    for (int i2 = threadIdx.x; i2 < NBINS; i2 += HIST_THREADS) {
        unsigned int s = lh[i2] + lh[NBINS + i2] + lh[2 * NBINS + i2] + lh[3 * NBINS + i2];
        atomicAdd(&g[i2], s);
    }
}

__global__ void normalize_kernel(const unsigned int* __restrict__ g,
                                 float* __restrict__ out, float total) {
    int i = blockIdx.x * blockDim.x + threadIdx.x;
    if (i < NBINS) out[i] = (float)g[i] / total;  // counts exact ints; total exact in f32
}

extern "C" void kernel_launch(void* const* d_in, const int* in_sizes, int n_in,
                              void* d_out, int out_size, void* d_ws, size_t ws_size,
                              hipStream_t stream) {
    const vfloat4* ev = (const vfloat4*)d_in[0]; // events [N,4] row-major -> one float4/event
    const int n = in_sizes[0] / 4;
    unsigned int* g = (unsigned int*)d_ws;       // 6 KiB of workspace
    float* out = (float*)d_out;

    zero_hist_kernel<<<(NBINS + 255) / 256, 256, 0, stream>>>(g);
    event_hist_kernel<<<HIST_BLOCKS, HIST_THREADS, 0, stream>>>(ev, g, n);
    normalize_kernel<<<(NBINS + 255) / 256, 256, 0, stream>>>(g, out, (float)n);
}

// Round 4
// 61.569 us; speedup vs baseline: 1.4327x; 1.1359x over previous
//
#include <hip/hip_runtime.h>

#define NBINS 1536            // 2 * 24 * 32
#define NSUB  8               // one LDS sub-histogram per PAIR of waves (48 KiB, 16 waves/block)
#define HIST_BLOCKS 512       // 2 blocks/CU x 16 waves = 32 waves/CU (full occupancy)
#define HIST_THREADS 1024

typedef float vfloat4 __attribute__((ext_vector_type(4)));

__global__ void zero_hist_kernel(unsigned int* __restrict__ g) {
    int i = blockIdx.x * blockDim.x + threadIdx.x;
    if (i < NBINS) g[i] = 0u;
}

__device__ __forceinline__ void bin_event(vfloat4 e, unsigned int* sub) {
    // replicate ref bit-exactly: f32 mul by BINS/SENSOR (both fold to 0.05f), trunc, clip
    int xb = (int)(e.x * (32.0f / 640.0f));
    int yb = (int)(e.y * (24.0f / 480.0f));
    xb = min(max(xb, 0), 31);
    yb = min(max(yb, 0), 23);
    int p = (e.w > 0.0f) ? 0 : 768;             // 768 = 24*32
    atomicAdd(&sub[p + (yb << 5) + xb], 1u);
}

__global__ __launch_bounds__(HIST_THREADS)
void event_hist_kernel(const vfloat4* __restrict__ ev, unsigned int* __restrict__ g, int n) {
    __shared__ unsigned int lh[NSUB * NBINS];   // 48 KiB
    for (int i = threadIdx.x; i < NSUB * NBINS; i += HIST_THREADS) lh[i] = 0u;
    __syncthreads();

    unsigned int* mysub = &lh[(threadIdx.x >> 7) * NBINS];  // 2 waves per sub-histogram
    const int stride = gridDim.x * HIST_THREADS;
    int i = blockIdx.x * HIST_THREADS + threadIdx.x;
    // 4 independent loads in flight per iteration
    for (; i + 3 * stride < n; i += 4 * stride) {
        vfloat4 a = ev[i];
        vfloat4 b = ev[i + stride];
        vfloat4 c = ev[i + 2 * stride];
        vfloat4 d = ev[i + 3 * stride];
        bin_event(a, mysub);
        bin_event(b, mysub);
        bin_event(c, mysub);
        bin_event(d, mysub);
    }
    for (; i < n; i += stride) {
        vfloat4 a = ev[i];
        bin_event(a, mysub);
    }
    __syncthreads();

    // flush block-local sums to the global histogram (1-2 bins per thread)
    for (int i2 = threadIdx.x; i2 < NBINS; i2 += HIST_THREADS) {
        unsigned int s = 0;
        #pragma unroll
        for (int c = 0; c < NSUB; ++c) s += lh[c * NBINS + i2];
        atomicAdd(&g[i2], s);
    }
}

__global__ void normalize_kernel(const unsigned int* __restrict__ g,
                                 float* __restrict__ out, float total) {
    int i = blockIdx.x * blockDim.x + threadIdx.x;
    if (i < NBINS) out[i] = (float)g[i] / total;  // counts exact ints; total exact in f32
}

extern "C" void kernel_launch(void* const* d_in, const int* in_sizes, int n_in,
                              void* d_out, int out_size, void* d_ws, size_t ws_size,
                              hipStream_t stream) {
    const vfloat4* ev = (const vfloat4*)d_in[0]; // events [N,4] row-major -> one float4/event
    const int n = in_sizes[0] / 4;
    unsigned int* g = (unsigned int*)d_ws;       // 6 KiB of workspace
    float* out = (float*)d_out;

    zero_hist_kernel<<<(NBINS + 255) / 256, 256, 0, stream>>>(g);
    event_hist_kernel<<<HIST_BLOCKS, HIST_THREADS, 0, stream>>>(ev, g, n);
    normalize_kernel<<<(NBINS + 255) / 256, 256, 0, stream>>>(g, out, (float)n);
}

// Round 5
// 60.352 us; speedup vs baseline: 1.4616x; 1.0202x over previous
//
#include <hip/hip_runtime.h>

#define NBINS 1536            // 2 * 24 * 32
#define NSUB  8               // one LDS sub-histogram per PAIR of waves (48 KiB, 16 waves/block)
#define HIST_BLOCKS 512       // 2 blocks/CU x 16 waves = 32 waves/CU (full occupancy)
#define HIST_THREADS 1024
#define RED_PER_BIN 8         // reduce kernel: threads per bin
#define RED_BINS_PER_BLOCK 128

typedef float vfloat4 __attribute__((ext_vector_type(4)));

__device__ __forceinline__ void bin_event(vfloat4 e, unsigned int* sub) {
    // replicate ref bit-exactly: f32 mul by BINS/SENSOR (both fold to 0.05f), trunc, clip
    int xb = (int)(e.x * (32.0f / 640.0f));
    int yb = (int)(e.y * (24.0f / 480.0f));
    xb = min(max(xb, 0), 31);
    yb = min(max(yb, 0), 23);
    int p = (e.w > 0.0f) ? 0 : 768;             // 768 = 24*32
    atomicAdd(&sub[p + (yb << 5) + xb], 1u);
}

template <bool USE_PARTIALS>
__global__ __launch_bounds__(HIST_THREADS)
void event_hist_kernel(const vfloat4* __restrict__ ev, unsigned int* __restrict__ gout, int n) {
    __shared__ unsigned int lh[NSUB * NBINS];   // 48 KiB
    for (int i = threadIdx.x; i < NSUB * NBINS; i += HIST_THREADS) lh[i] = 0u;
    __syncthreads();

    unsigned int* mysub = &lh[(threadIdx.x >> 7) * NBINS];  // 2 waves per sub-histogram
    const int stride = gridDim.x * HIST_THREADS;
    int i = blockIdx.x * HIST_THREADS + threadIdx.x;
    // 4 independent loads in flight per iteration
    for (; i + 3 * stride < n; i += 4 * stride) {
        vfloat4 a = ev[i];
        vfloat4 b = ev[i + stride];
        vfloat4 c = ev[i + 2 * stride];
        vfloat4 d = ev[i + 3 * stride];
        bin_event(a, mysub);
        bin_event(b, mysub);
        bin_event(c, mysub);
        bin_event(d, mysub);
    }
    for (; i < n; i += stride) {
        vfloat4 a = ev[i];
        bin_event(a, mysub);
    }
    __syncthreads();

    // flush block-local sums
    if (USE_PARTIALS) {
        // non-atomic coalesced partials: gout = partial[HIST_BLOCKS][NBINS]
        unsigned int* mypart = gout + (size_t)blockIdx.x * NBINS;
        for (int i2 = threadIdx.x; i2 < NBINS; i2 += HIST_THREADS) {
            unsigned int s = 0;
            #pragma unroll
            for (int c = 0; c < NSUB; ++c) s += lh[c * NBINS + i2];
            mypart[i2] = s;
        }
    } else {
        for (int i2 = threadIdx.x; i2 < NBINS; i2 += HIST_THREADS) {
            unsigned int s = 0;
            #pragma unroll
            for (int c = 0; c < NSUB; ++c) s += lh[c * NBINS + i2];
            atomicAdd(&gout[i2], s);
        }
    }
}

// 12 blocks x 1024 threads: 128 bins/block, 8 threads/bin summing 64 partials each
__global__ __launch_bounds__(1024)
void reduce_norm_kernel(const unsigned int* __restrict__ partial,
                        float* __restrict__ out, float total) {
    __shared__ unsigned int red[RED_PER_BIN * RED_BINS_PER_BLOCK];
    const int b   = threadIdx.x & (RED_BINS_PER_BLOCK - 1);
    const int j   = threadIdx.x >> 7;                    // [0, 8)
    const int bin = blockIdx.x * RED_BINS_PER_BLOCK + b;
    unsigned int s = 0;
    #pragma unroll 8
    for (int c = j; c < HIST_BLOCKS; c += RED_PER_BIN)
        s += partial[(size_t)c * NBINS + bin];           // coalesced across b
    red[threadIdx.x] = s;
    __syncthreads();
    if (threadIdx.x < RED_BINS_PER_BLOCK) {
        unsigned int t = 0;
        #pragma unroll
        for (int k = 0; k < RED_PER_BIN; ++k) t += red[k * RED_BINS_PER_BLOCK + b];
        out[bin] = (float)t / total;   // exact ints, exact total -> bit-exact vs ref
    }
}

__global__ void zero_hist_kernel(unsigned int* __restrict__ g) {
    int i = blockIdx.x * blockDim.x + threadIdx.x;
    if (i < NBINS) g[i] = 0u;
}

__global__ void normalize_kernel(const unsigned int* __restrict__ g,
                                 float* __restrict__ out, float total) {
    int i = blockIdx.x * blockDim.x + threadIdx.x;
    if (i < NBINS) out[i] = (float)g[i] / total;
}

extern "C" void kernel_launch(void* const* d_in, const int* in_sizes, int n_in,
                              void* d_out, int out_size, void* d_ws, size_t ws_size,
                              hipStream_t stream) {
    const vfloat4* ev = (const vfloat4*)d_in[0]; // events [N,4] row-major -> one float4/event
    const int n = in_sizes[0] / 4;
    float* out = (float*)d_out;

    const size_t need = (size_t)HIST_BLOCKS * NBINS * sizeof(unsigned int);  // 3 MiB
    if (ws_size >= need) {
        unsigned int* partial = (unsigned int*)d_ws;
        event_hist_kernel<true><<<HIST_BLOCKS, HIST_THREADS, 0, stream>>>(ev, partial, n);
        reduce_norm_kernel<<<NBINS / RED_BINS_PER_BLOCK, 1024, 0, stream>>>(partial, out, (float)n);
    } else {
        // fallback: round-4 atomic path
        unsigned int* g = (unsigned int*)d_ws;
        zero_hist_kernel<<<(NBINS + 255) / 256, 256, 0, stream>>>(g);
        event_hist_kernel<false><<<HIST_BLOCKS, HIST_THREADS, 0, stream>>>(ev, g, n);
        normalize_kernel<<<(NBINS + 255) / 256, 256, 0, stream>>>(g, out, (float)n);
    }
}

// Round 6
// 59.319 us; speedup vs baseline: 1.4870x; 1.0174x over previous
//
#include <hip/hip_runtime.h>

#define NBINS 1536            // 2 * 24 * 32
#define NSUB  8               // one LDS sub-histogram per PAIR of waves (48 KiB, 16 waves/block)
#define HIST_BLOCKS 512       // 2 blocks/CU x 16 waves = 32 waves/CU (full occupancy)
#define HIST_THREADS 1024
#define RED_BLOCKS 48         // reduce: 32 bins/block, 8 threads/bin over 512 partials
#define RED_THREADS 256
#define RED_BINS_PER_BLOCK 32
#define RED_PER_BIN 8

typedef float vfloat4 __attribute__((ext_vector_type(4)));

__device__ __forceinline__ void bin_event(vfloat4 e, unsigned int* sub) {
    // replicate ref bit-exactly: f32 mul by BINS/SENSOR (both fold to 0.05f), trunc, clip
    int xb = (int)(e.x * (32.0f / 640.0f));
    int yb = (int)(e.y * (24.0f / 480.0f));
    xb = min(max(xb, 0), 31);
    yb = min(max(yb, 0), 23);
    int p = (e.w > 0.0f) ? 0 : 768;             // 768 = 24*32
    atomicAdd(&sub[p + (yb << 5) + xb], 1u);
}

__global__ __launch_bounds__(HIST_THREADS)
void event_hist_kernel(const vfloat4* __restrict__ ev, unsigned int* __restrict__ gout, int n) {
    __shared__ unsigned int lh[NSUB * NBINS];   // 48 KiB
    for (int i = threadIdx.x; i < NSUB * NBINS; i += HIST_THREADS) lh[i] = 0u;
    __syncthreads();

    unsigned int* mysub = &lh[(threadIdx.x >> 7) * NBINS];  // 2 waves per sub-histogram
    const int stride = gridDim.x * HIST_THREADS;
    int i = blockIdx.x * HIST_THREADS + threadIdx.x;

    // software-pipelined: 8 loads in flight (current 4 processing, next 4 fetching)
    if (i + 3 * stride < n) {
        vfloat4 a = ev[i];
        vfloat4 b = ev[i + stride];
        vfloat4 c = ev[i + 2 * stride];
        vfloat4 d = ev[i + 3 * stride];
        i += 4 * stride;
        for (; i + 3 * stride < n; i += 4 * stride) {
            vfloat4 a2 = ev[i];
            vfloat4 b2 = ev[i + stride];
            vfloat4 c2 = ev[i + 2 * stride];
            vfloat4 d2 = ev[i + 3 * stride];
            bin_event(a, mysub);
            bin_event(b, mysub);
            bin_event(c, mysub);
            bin_event(d, mysub);
            a = a2; b = b2; c = c2; d = d2;
        }
        bin_event(a, mysub);
        bin_event(b, mysub);
        bin_event(c, mysub);
        bin_event(d, mysub);
    }
    for (; i < n; i += stride) {
        vfloat4 a = ev[i];
        bin_event(a, mysub);
    }
    __syncthreads();

    // non-atomic coalesced partials: gout = partial[HIST_BLOCKS][NBINS]
    unsigned int* mypart = gout + (size_t)blockIdx.x * NBINS;
    for (int i2 = threadIdx.x; i2 < NBINS; i2 += HIST_THREADS) {
        unsigned int s = 0;
        #pragma unroll
        for (int c = 0; c < NSUB; ++c) s += lh[c * NBINS + i2];
        mypart[i2] = s;
    }
}

// 48 blocks x 256 threads: 32 bins/block, 8 threads/bin summing 64 partials each
__global__ __launch_bounds__(RED_THREADS)
void reduce_norm_kernel(const unsigned int* __restrict__ partial,
                        float* __restrict__ out, float total) {
    __shared__ unsigned int red[RED_THREADS];
    const int b   = threadIdx.x & (RED_BINS_PER_BLOCK - 1);
    const int j   = threadIdx.x >> 5;                    // [0, 8)
    const int bin = blockIdx.x * RED_BINS_PER_BLOCK + b;
    unsigned int s = 0;
    #pragma unroll 8
    for (int c = j; c < HIST_BLOCKS; c += RED_PER_BIN)
        s += partial[(size_t)c * NBINS + bin];           // coalesced across b
    red[threadIdx.x] = s;
    __syncthreads();
    if (threadIdx.x < RED_BINS_PER_BLOCK) {
        unsigned int t = 0;
        #pragma unroll
        for (int k = 0; k < RED_PER_BIN; ++k) t += red[k * RED_BINS_PER_BLOCK + b];
        out[bin] = (float)t / total;   // exact ints, exact total -> bit-exact vs ref
    }
}

extern "C" void kernel_launch(void* const* d_in, const int* in_sizes, int n_in,
                              void* d_out, int out_size, void* d_ws, size_t ws_size,
                              hipStream_t stream) {
    const vfloat4* ev = (const vfloat4*)d_in[0]; // events [N,4] row-major -> one float4/event
    const int n = in_sizes[0] / 4;
    float* out = (float*)d_out;
    unsigned int* partial = (unsigned int*)d_ws; // 3 MiB of workspace

    event_hist_kernel<<<HIST_BLOCKS, HIST_THREADS, 0, stream>>>(ev, partial, n);
    reduce_norm_kernel<<<RED_BLOCKS, RED_THREADS, 0, stream>>>(partial, out, (float)n);
}